// Round 3
// baseline (631.413 us; speedup 1.0000x reference)
//
#include <hip/hip_runtime.h>
#include <hip/hip_bf16.h>
#include <math.h>

#define N_SKILLS 16
#define RLORA 16
#define IN_F 1024
#define OUT_F 1024
#define KD 1024
#define ND 1024

typedef __attribute__((ext_vector_type(8))) short s16x8;
typedef __attribute__((ext_vector_type(4))) float f32x4;

__device__ __forceinline__ unsigned short f2bf(float f) {
  unsigned int u = __float_as_uint(f);
  u += 0x7fffu + ((u >> 16) & 1u);
  return (unsigned short)(u >> 16);
}

#define GLDS(gsrc, ldst)                                                       \
  __builtin_amdgcn_global_load_lds(                                            \
      (const __attribute__((address_space(1))) unsigned int*)(gsrc),           \
      (__attribute__((address_space(3))) unsigned int*)(ldst), 16, 0, 0)

// ---------------------------------------------------------------------------
// Kernel 1: routing -> per-sample LoRA weights wA (B,IN_F,R), wB (B,R,OUT_F)
// ---------------------------------------------------------------------------
__global__ void route_wab_kernel(const float* __restrict__ skill_logits,
                                 const int* __restrict__ task_ids,
                                 const float* __restrict__ Askills,
                                 const float* __restrict__ Bskills,
                                 float* __restrict__ wA, float* __restrict__ wB) {
  __shared__ float l[N_SKILLS];
  const int bx = blockIdx.x;
  const int b = bx & 15;
  const int doB = bx >> 4;
  const int tid = threadIdx.x;
  if (tid == 0) {
    int t = task_ids[b];
    float tmp[N_SKILLS];
    float s = 0.f;
    for (int k = 0; k < N_SKILLS; ++k) {
      float v = 1.f / (1.f + expf(-skill_logits[t * N_SKILLS + k]));
      tmp[k] = v;
      s += v;
    }
    float inv = 1.f / (s + 1e-12f);
    for (int k = 0; k < N_SKILLS; ++k) l[k] = tmp[k] * inv;
  }
  __syncthreads();
  const float* src = doB ? Bskills : Askills;
  float* dst = (doB ? wB : wA) + b * 16384;
  for (int j = tid; j < 16384; j += 256) {
    float acc = 0.f;
#pragma unroll
    for (int k = 0; k < N_SKILLS; ++k) acc += l[k] * src[k * 16384 + j];
    dst[j] = acc;
  }
}

// ---------------------------------------------------------------------------
// Tile image layout (per 256x64 bf16 tile = 16384 shorts):
//   element (row, k):  region = (row>>6)*2 + (k>>5)          (8 regions)
//   off = region*2048 + ((k>>3)&3)*512 + (row&63)*8 + (k&7)
// One GLD "call" g covers regions [2g, 2g+2) = rows [g*64,+64), all k.
// ---------------------------------------------------------------------------

// Kernel 2a: A fp32 -> bf16 tiled images. Block = one (mt, kt) tile.
__global__ void aconv_kernel(const float* __restrict__ A,
                             unsigned short* __restrict__ At) {
  __shared__ unsigned short img[16384];
  const int t = blockIdx.x;  // mt*16 + kt
  const int mt = t >> 4, kt = t & 15;
  const int tid = threadIdx.x;
  const int rowl = tid >> 2, kquad = tid & 3;
  const int ks = kquad >> 1;
#pragma unroll
  for (int rp = 0; rp < 4; ++rp) {
    const float* src =
        A + (size_t)(mt * 256 + rp * 64 + rowl) * KD + kt * 64 + kquad * 16;
    f32x4 v0 = *(const f32x4*)(src);
    f32x4 v1 = *(const f32x4*)(src + 4);
    f32x4 v2 = *(const f32x4*)(src + 8);
    f32x4 v3 = *(const f32x4*)(src + 12);
    s16x8 lo, hi;
#pragma unroll
    for (int j = 0; j < 4; ++j) {
      lo[j] = (short)f2bf(v0[j]);
      lo[j + 4] = (short)f2bf(v1[j]);
      hi[j] = (short)f2bf(v2[j]);
      hi[j + 4] = (short)f2bf(v3[j]);
    }
    const int base = (rp * 2 + ks) * 2048 + rowl * 8;
    *(s16x8*)&img[base + ((kquad & 1) * 2) * 512] = lo;
    *(s16x8*)&img[base + ((kquad & 1) * 2 + 1) * 512] = hi;
  }
  __syncthreads();
  unsigned short* dst = At + (size_t)t * 16384;
#pragma unroll
  for (int w = 0; w < 8; ++w)
    *(s16x8*)&dst[(w * 256 + tid) * 8] = *(const s16x8*)&img[(w * 256 + tid) * 8];
}

// Kernel 2b: W_eff = weight + (1/R)*(wA@wB)^T, bf16 tiled images.
// Block = (b, nt, kt) tile: 256 out-cols x 64 i. grid = 16*4*16 = 1024.
__global__ void weff_kernel(const float* __restrict__ weight,
                            const float* __restrict__ wA,
                            const float* __restrict__ wB,
                            unsigned short* __restrict__ Wt) {
  __shared__ float wBs[16][256];
  __shared__ float wAs[64][16];
  __shared__ unsigned short img[16384];
  const int t = blockIdx.x;  // b*64 + nt*16 + kt
  const int b = t >> 6;
  const int nt = (t >> 4) & 3;
  const int kt = t & 15;
  const int tid = threadIdx.x;
  for (int j = tid; j < 4096; j += 256)
    wBs[j >> 8][j & 255] = wB[b * 16384 + (j >> 8) * OUT_F + nt * 256 + (j & 255)];
  for (int j = tid; j < 1024; j += 256)
    wAs[j >> 4][j & 15] = wA[b * 16384 + (kt * 64 + (j >> 4)) * RLORA + (j & 15)];
  __syncthreads();
  const int ol = tid >> 2, kquad = tid & 3;
  const int ks = kquad >> 1;
#pragma unroll
  for (int rp = 0; rp < 4; ++rp) {
    const int o_loc = rp * 64 + ol;  // tile-local out-col 0..255
    const float* src =
        weight + (size_t)(nt * 256 + o_loc) * IN_F + kt * 64 + kquad * 16;
    f32x4 v0 = *(const f32x4*)(src);
    f32x4 v1 = *(const f32x4*)(src + 4);
    f32x4 v2 = *(const f32x4*)(src + 8);
    f32x4 v3 = *(const f32x4*)(src + 12);
    float wv[16];
#pragma unroll
    for (int j = 0; j < 4; ++j) {
      wv[j] = v0[j];
      wv[j + 4] = v1[j];
      wv[j + 8] = v2[j];
      wv[j + 12] = v3[j];
    }
    float wbo[16];
#pragma unroll
    for (int r = 0; r < 16; ++r) wbo[r] = wBs[r][o_loc];
    unsigned short res[16];
#pragma unroll
    for (int j = 0; j < 16; ++j) {
      const int il = kquad * 16 + j;
      float acc = 0.f;
#pragma unroll
      for (int r = 0; r < 16; ++r) acc += wAs[il][r] * wbo[r];
      res[j] = f2bf(wv[j] + acc * 0.0625f);
    }
    s16x8 lo, hi;
#pragma unroll
    for (int j = 0; j < 8; ++j) {
      lo[j] = (short)res[j];
      hi[j] = (short)res[j + 8];
    }
    const int base = (rp * 2 + ks) * 2048 + ol * 8;
    *(s16x8*)&img[base + ((kquad & 1) * 2) * 512] = lo;
    *(s16x8*)&img[base + ((kquad & 1) * 2 + 1) * 512] = hi;
  }
  __syncthreads();
  unsigned short* dst = Wt + (size_t)t * 16384;
#pragma unroll
  for (int w = 0; w < 8; ++w)
    *(s16x8*)&dst[(w * 256 + tid) * 8] = *(const s16x8*)&img[(w * 256 + tid) * 8];
}

// ---------------------------------------------------------------------------
// Kernel 3: 256x256 8-phase GEMM, BK=64, 8 waves (2Mx4N), counted vmcnt.
// Per K-tile: 4 phases x 16 MFMA. GLD issue (into other buffer):
//   P0: B'c2,c3  P1: A'c0,c2  P2: A'c1,c3  P3: B''c0,c1
// Reads: P0: a1<-Ac[mh0][ks1], b[4..7]<-Bc[ks1]; P1: a0<-Ac[mh1][ks0];
//        P2: a1<-Ac[mh1][ks1]; P3: a0<-An[mh0][ks0], b[0..3]<-Bn[ks0].
// Gates: vmcnt(4) end-P0 (gates Ac1,c3); vmcnt(2) end-P2 (gates Bn*, An0,c2).
// ---------------------------------------------------------------------------
#define BAR() __builtin_amdgcn_s_barrier()
#define LGKM0()                                                \
  {                                                            \
    asm volatile("s_waitcnt lgkmcnt(0)" ::: "memory");         \
    __builtin_amdgcn_sched_barrier(0);                         \
  }
#define VMCNT(N) asm volatile("s_waitcnt vmcnt(" #N ")" ::: "memory")
#define PRIO1() __builtin_amdgcn_s_setprio(1)
#define PRIO0() __builtin_amdgcn_s_setprio(0)

#define GLD_CALL(LDSBUF, GBASE, CALLIDX)                                       \
  GLDS((GBASE) + (CALLIDX) * 4096 + wid * 512 + lane * 8,                      \
       &(LDSBUF)[(CALLIDX) * 4096 + wid * 512])

#define READ_A(BANK, LDSBUF, MH, KS)                                           \
  {                                                                            \
    _Pragma("unroll") for (int mf_ = 0; mf_ < 4; ++mf_)                        \
        BANK[mf_] = *(const s16x8*)&(                                          \
            LDSBUF)[((wr2 + (MH)) * 2 + (KS)) * 2048 + kq512 +                 \
                    (mf_ * 16 + l15) * 8];                                     \
  }

#define READ_B(LDSBUF, KS)                                                     \
  {                                                                            \
    _Pragma("unroll") for (int nf_ = 0; nf_ < 4; ++nf_)                        \
        bfr[(KS)*4 + nf_] = *(const s16x8*)&(                                  \
            LDSBUF)[(wc2 + (KS)) * 2048 + kq512 + (nf_ * 16 + l15) * 8];       \
  }

#define MFMA16(MH, ABANK, BOFF)                                                \
  {                                                                            \
    _Pragma("unroll") for (int mf_ = 0; mf_ < 4; ++mf_)                        \
        _Pragma("unroll") for (int nf_ = 0; nf_ < 4; ++nf_)                    \
            acc[(MH)*4 + mf_][nf_] = __builtin_amdgcn_mfma_f32_16x16x32_bf16(  \
                ABANK[mf_], bfr[(BOFF) + nf_], acc[(MH)*4 + mf_][nf_], 0, 0,   \
                0);                                                            \
  }

#define TILE_BODY(ASC, BSC, ASN, BSN, T)                                       \
  {                                                                            \
    const int tn_ = ((T) + 1 < 16) ? (T) + 1 : 15;                             \
    const int tnn_ = ((T) + 2 < 16) ? (T) + 2 : 15;                            \
    const unsigned short* Anx = Abase + (size_t)tn_ * 16384;                   \
    const unsigned short* Bnx = Bbase + (size_t)tn_ * 16384;                   \
    const unsigned short* Bnn = Bbase + (size_t)tnn_ * 16384;                  \
    /* P0 */                                                                   \
    READ_A(a1, ASC, 0, 1);                                                     \
    READ_B(BSC, 1);                                                            \
    GLD_CALL(BSN, Bnx, 2);                                                     \
    GLD_CALL(BSN, Bnx, 3);                                                     \
    BAR();                                                                     \
    LGKM0();                                                                   \
    PRIO1(); MFMA16(0, a0, 0); PRIO0();                                        \
    VMCNT(4);                                                                  \
    BAR();                                                                     \
    /* P1 */                                                                   \
    READ_A(a0, ASC, 1, 0);                                                     \
    GLD_CALL(ASN, Anx, 0);                                                     \
    GLD_CALL(ASN, Anx, 2);                                                     \
    BAR();                                                                     \
    LGKM0();                                                                   \
    PRIO1(); MFMA16(0, a1, 4); PRIO0();                                        \
    BAR();                                                                     \
    /* P2 */                                                                   \
    READ_A(a1, ASC, 1, 1);                                                     \
    GLD_CALL(ASN, Anx, 1);                                                     \
    GLD_CALL(ASN, Anx, 3);                                                     \
    BAR();                                                                     \
    LGKM0();                                                                   \
    PRIO1(); MFMA16(1, a0, 0); PRIO0();                                        \
    VMCNT(2);                                                                  \
    BAR();                                                                     \
    /* P3 */                                                                   \
    READ_A(a0, ASN, 0, 0);                                                     \
    READ_B(BSN, 0);                                                            \
    GLD_CALL(BSC, Bnn, 0);                                                     \
    GLD_CALL(BSC, Bnn, 1);                                                     \
    BAR();                                                                     \
    LGKM0();                                                                   \
    PRIO1(); MFMA16(1, a1, 4); PRIO0();                                        \
    BAR();                                                                     \
  }

__global__ __launch_bounds__(512) void gemm8_kernel(
    const unsigned short* __restrict__ At, const unsigned short* __restrict__ Wt,
    const float* __restrict__ bias, float* __restrict__ C) {
  __shared__ __align__(16) unsigned short Asm[2][16384];
  __shared__ __align__(16) unsigned short Bsm[2][16384];
  unsigned short* const As0 = Asm[0];
  unsigned short* const As1 = Asm[1];
  unsigned short* const Bs0 = Bsm[0];
  unsigned short* const Bs1 = Bsm[1];

  const int orig = blockIdx.x;
  const int bid = (orig & 7) * 128 + (orig >> 3);  // XCD swizzle, 1024%8==0
  const int mt = bid >> 2;                         // 0..255
  const int nt = bid & 3;                          // 0..3
  const int batch = mt >> 4;
  const unsigned short* Abase = At + (size_t)mt * 16 * 16384;
  const unsigned short* Bbase = Wt + ((size_t)batch * 4 + nt) * 16 * 16384;

  const int tid = threadIdx.x;
  const int lane = tid & 63;
  const int wid = tid >> 6;
  const int wr = wid >> 2;  // 0..1
  const int wc = wid & 3;   // 0..3
  const int wr2 = wr * 2;
  const int wc2 = wc * 2;
  const int l15 = lane & 15;
  const int kq = lane >> 4;
  const int kq512 = kq * 512;

  f32x4 acc[8][4] = {};
  s16x8 a0[4], a1[4], bfr[8];

  // Prologue: stage tile 0 fully + B(1) calls 0,1; gate; pre-read a0/b[0..3].
  GLD_CALL(Bs0, Bbase, 0);
  GLD_CALL(Bs0, Bbase, 1);
  GLD_CALL(Bs0, Bbase, 2);
  GLD_CALL(Bs0, Bbase, 3);
  GLD_CALL(As0, Abase, 0);
  GLD_CALL(As0, Abase, 2);
  GLD_CALL(As0, Abase, 1);
  GLD_CALL(As0, Abase, 3);
  {
    const unsigned short* B1 = Bbase + 16384;
    GLD_CALL(Bs1, B1, 0);
    GLD_CALL(Bs1, B1, 1);
  }
  VMCNT(2);
  BAR();
  READ_A(a0, As0, 0, 0);
  READ_B(Bs0, 0);

#pragma unroll 1
  for (int it = 0; it < 8; ++it) {
    const int t0 = it * 2;
    TILE_BODY(As0, Bs0, As1, Bs1, t0);
    TILE_BODY(As1, Bs1, As0, Bs0, t0 + 1);
  }

  // Epilogue: bias add + store fp32
  const int m0 = mt * 256, n0 = nt * 256;
#pragma unroll
  for (int n = 0; n < 4; ++n) {
    const int col = n0 + wc * 64 + n * 16 + l15;
    const float bv = bias[col];
#pragma unroll
    for (int m = 0; m < 8; ++m) {
      const int row = m0 + wr * 128 + m * 16 + kq * 4;
#pragma unroll
      for (int j = 0; j < 4; ++j)
        C[(size_t)(row + j) * ND + col] = acc[m][n][j] + bv;
    }
  }
}

// ---------------------------------------------------------------------------
extern "C" void kernel_launch(void* const* d_in, const int* in_sizes, int n_in,
                              void* d_out, int out_size, void* d_ws,
                              size_t ws_size, hipStream_t stream) {
  const float* input = (const float*)d_in[0];
  const float* skill_logits = (const float*)d_in[1];
  const float* weight = (const float*)d_in[2];
  const float* bias = (const float*)d_in[3];
  const float* Askills = (const float*)d_in[4];
  const float* Bskills = (const float*)d_in[5];
  const int* task_ids = (const int*)d_in[6];

  float* wA = (float*)d_ws;                                   // 1 MB
  float* wB = wA + 16 * 16384;                                // 1 MB
  unsigned short* Wt = (unsigned short*)(wB + 16 * 16384);    // 32 MB
  unsigned short* At = Wt + 16ull * 1024 * 1024;              // 128 MB

  route_wab_kernel<<<32, 256, 0, stream>>>(skill_logits, task_ids, Askills,
                                           Bskills, wA, wB);
  aconv_kernel<<<4096, 256, 0, stream>>>(input, At);
  weff_kernel<<<1024, 256, 0, stream>>>(weight, wA, wB, Wt);
  gemm8_kernel<<<1024, 512, 0, stream>>>(At, Wt, bias, (float*)d_out);
}

// Round 4
// 376.991 us; speedup vs baseline: 1.6749x; 1.6749x over previous
//
#include <hip/hip_runtime.h>
#include <hip/hip_bf16.h>
#include <math.h>

#define N_SKILLS 16
#define RLORA 16
#define IN_F 1024
#define OUT_F 1024
#define KD 1024
#define ND 1024

typedef __attribute__((ext_vector_type(8))) short s16x8;
typedef __attribute__((ext_vector_type(4))) float f32x4;

__device__ __forceinline__ unsigned short f2bf(float f) {
  unsigned int u = __float_as_uint(f);
  u += 0x7fffu + ((u >> 16) & 1u);
  return (unsigned short)(u >> 16);
}

#define GLDS(gsrc, ldst)                                                       \
  __builtin_amdgcn_global_load_lds(                                            \
      (const __attribute__((address_space(1))) unsigned int*)(gsrc),           \
      (__attribute__((address_space(3))) unsigned int*)(ldst), 16, 0, 0)

// ---------------------------------------------------------------------------
// Kernel 1: routing -> per-sample LoRA weights wA (B,IN_F,R), wB (B,R,OUT_F)
// ---------------------------------------------------------------------------
__global__ void route_wab_kernel(const float* __restrict__ skill_logits,
                                 const int* __restrict__ task_ids,
                                 const float* __restrict__ Askills,
                                 const float* __restrict__ Bskills,
                                 float* __restrict__ wA, float* __restrict__ wB) {
  __shared__ float l[N_SKILLS];
  const int bx = blockIdx.x;
  const int b = bx & 15;
  const int doB = bx >> 4;
  const int tid = threadIdx.x;
  if (tid == 0) {
    int t = task_ids[b];
    float tmp[N_SKILLS];
    float s = 0.f;
    for (int k = 0; k < N_SKILLS; ++k) {
      float v = 1.f / (1.f + expf(-skill_logits[t * N_SKILLS + k]));
      tmp[k] = v;
      s += v;
    }
    float inv = 1.f / (s + 1e-12f);
    for (int k = 0; k < N_SKILLS; ++k) l[k] = tmp[k] * inv;
  }
  __syncthreads();
  const float* src = doB ? Bskills : Askills;
  float* dst = (doB ? wB : wA) + b * 16384;
  for (int j = tid; j < 16384; j += 256) {
    float acc = 0.f;
#pragma unroll
    for (int k = 0; k < N_SKILLS; ++k) acc += l[k] * src[k * 16384 + j];
    dst[j] = acc;
  }
}

// ---------------------------------------------------------------------------
// Tile image layout (per 256x64 bf16 tile = 16384 shorts):
//   element (row, k):  region = (row>>6)*2 + (k>>5)          (8 regions)
//   off = region*2048 + ((k>>3)&3)*512 + (row&63)*8 + (k&7)
// One GLD "call" g covers regions [2g, 2g+2) = rows [g*64,+64), all k.
// ---------------------------------------------------------------------------

// Kernel 2a: A fp32 -> bf16 tiled images. Block = one 64-row quarter of a
// (mt,kt) tile. Direct global writes (non-overlapping, 256B runs per wave).
__global__ __launch_bounds__(256) void aconv_kernel(
    const float* __restrict__ A, unsigned short* __restrict__ At) {
  const int bx = blockIdx.x;  // (mt*16+kt)*4 + rp
  const int rp = bx & 3;
  const int tk = bx >> 2;
  const int mt = tk >> 4, kt = tk & 15;
  const int tid = threadIdx.x;
  const int rowl = tid >> 2, kquad = tid & 3;
  const int ks = kquad >> 1;
  const float* src =
      A + (size_t)(mt * 256 + rp * 64 + rowl) * KD + kt * 64 + kquad * 16;
  f32x4 v0 = *(const f32x4*)(src);
  f32x4 v1 = *(const f32x4*)(src + 4);
  f32x4 v2 = *(const f32x4*)(src + 8);
  f32x4 v3 = *(const f32x4*)(src + 12);
  s16x8 lo, hi;
#pragma unroll
  for (int j = 0; j < 4; ++j) {
    lo[j] = (short)f2bf(v0[j]);
    lo[j + 4] = (short)f2bf(v1[j]);
    hi[j] = (short)f2bf(v2[j]);
    hi[j + 4] = (short)f2bf(v3[j]);
  }
  unsigned short* dst = At + (size_t)tk * 16384 + (rp * 2 + ks) * 2048 +
                        (kquad & 1) * 1024 + rowl * 8;
  *(s16x8*)&dst[0] = lo;
  *(s16x8*)&dst[512] = hi;
}

// Kernel 2b: W_eff = weight + (1/R)*(wA@wB)^T, bf16 tiled images.
// Block = 64-col quarter of a (b,nt,kt) tile. grid = 16*4*16*4 = 4096.
__global__ __launch_bounds__(256) void weff_kernel(
    const float* __restrict__ weight, const float* __restrict__ wA,
    const float* __restrict__ wB, unsigned short* __restrict__ Wt) {
  __shared__ float wBs[16][64];
  __shared__ float wAs[64][16];
  const int bx = blockIdx.x;  // ((b*4+nt)*16+kt)*4 + rp
  const int rp = bx & 3;
  const int t = bx >> 2;  // b*64 + nt*16 + kt
  const int b = t >> 6;
  const int nt = (t >> 4) & 3;
  const int kt = t & 15;
  const int tid = threadIdx.x;
  for (int j = tid; j < 1024; j += 256) {
    wBs[j >> 6][j & 63] =
        wB[b * 16384 + (j >> 6) * OUT_F + nt * 256 + rp * 64 + (j & 63)];
    wAs[j >> 4][j & 15] = wA[b * 16384 + kt * 1024 + j];
  }
  __syncthreads();
  const int ol = tid >> 2, kquad = tid & 3;
  const int ks = kquad >> 1;
  const int o_loc = rp * 64 + ol;  // tile-local out-col
  const float* src =
      weight + (size_t)(nt * 256 + o_loc) * IN_F + kt * 64 + kquad * 16;
  f32x4 v0 = *(const f32x4*)(src);
  f32x4 v1 = *(const f32x4*)(src + 4);
  f32x4 v2 = *(const f32x4*)(src + 8);
  f32x4 v3 = *(const f32x4*)(src + 12);
  float wv[16];
#pragma unroll
  for (int j = 0; j < 4; ++j) {
    wv[j] = v0[j];
    wv[j + 4] = v1[j];
    wv[j + 8] = v2[j];
    wv[j + 12] = v3[j];
  }
  float wbo[16];
#pragma unroll
  for (int r = 0; r < 16; ++r) wbo[r] = wBs[r][ol];
  unsigned short res[16];
#pragma unroll
  for (int j = 0; j < 16; ++j) {
    const int il = kquad * 16 + j;
    float acc = 0.f;
#pragma unroll
    for (int r = 0; r < 16; ++r) acc += wAs[il][r] * wbo[r];
    res[j] = f2bf(wv[j] + acc * 0.0625f);
  }
  s16x8 lo, hi;
#pragma unroll
  for (int j = 0; j < 8; ++j) {
    lo[j] = (short)res[j];
    hi[j] = (short)res[j + 8];
  }
  unsigned short* dst = Wt + (size_t)t * 16384 + (rp * 2 + ks) * 2048 +
                        (kquad & 1) * 1024 + ol * 8;
  *(s16x8*)&dst[0] = lo;
  *(s16x8*)&dst[512] = hi;
}

// ---------------------------------------------------------------------------
// Kernel 3: 256x256 8-phase GEMM, BK=64, 8 waves (2Mx4N), counted vmcnt.
// Per K-tile: 4 phases x 16 MFMA. GLD issue (into other buffer):
//   P0: B'c2,c3  P1: A'c0,c2  P2: A'c1,c3  P3: B''c0,c1
// Gates: vmcnt(4) end-P0 (drains A-cur c1,c3); vmcnt(2) end-P2 (drains
// B-next c0..c3 + A-next c0,c2) -- derived from per-wave issue order.
// ---------------------------------------------------------------------------
#define BAR() __builtin_amdgcn_s_barrier()
#define LGKM0()                                                \
  {                                                            \
    asm volatile("s_waitcnt lgkmcnt(0)" ::: "memory");         \
    __builtin_amdgcn_sched_barrier(0);                         \
  }
#define VMCNT(N) asm volatile("s_waitcnt vmcnt(" #N ")" ::: "memory")
#define PRIO1() __builtin_amdgcn_s_setprio(1)
#define PRIO0() __builtin_amdgcn_s_setprio(0)

#define GLD_CALL(LDSBUF, GBASE, CALLIDX)                                       \
  GLDS((GBASE) + (CALLIDX) * 4096 + wid * 512 + lane * 8,                      \
       &(LDSBUF)[(CALLIDX) * 4096 + wid * 512])

#define READ_A(BANK, LDSBUF, MH, KS)                                           \
  {                                                                            \
    _Pragma("unroll") for (int mf_ = 0; mf_ < 4; ++mf_)                        \
        BANK[mf_] = *(const s16x8*)&(                                          \
            LDSBUF)[((wr2 + (MH)) * 2 + (KS)) * 2048 + kq512 +                 \
                    (mf_ * 16 + l15) * 8];                                     \
  }

#define READ_B(LDSBUF, KS)                                                     \
  {                                                                            \
    _Pragma("unroll") for (int nf_ = 0; nf_ < 4; ++nf_)                        \
        bfr[(KS)*4 + nf_] = *(const s16x8*)&(                                  \
            LDSBUF)[(wc2 + (KS)) * 2048 + kq512 + (nf_ * 16 + l15) * 8];       \
  }

#define MFMA16(MH, ABANK, BOFF)                                                \
  {                                                                            \
    _Pragma("unroll") for (int mf_ = 0; mf_ < 4; ++mf_)                        \
        _Pragma("unroll") for (int nf_ = 0; nf_ < 4; ++nf_)                    \
            acc[(MH)*4 + mf_][nf_] = __builtin_amdgcn_mfma_f32_16x16x32_bf16(  \
                ABANK[mf_], bfr[(BOFF) + nf_], acc[(MH)*4 + mf_][nf_], 0, 0,   \
                0);                                                            \
  }

#define TILE_BODY(ASC, BSC, ASN, BSN, T)                                       \
  {                                                                            \
    const int tn_ = ((T) + 1 < 16) ? (T) + 1 : 15;                             \
    const int tnn_ = ((T) + 2 < 16) ? (T) + 2 : 15;                            \
    const unsigned short* Anx = Abase + (size_t)tn_ * 16384;                   \
    const unsigned short* Bnx = Bbase + (size_t)tn_ * 16384;                   \
    const unsigned short* Bnn = Bbase + (size_t)tnn_ * 16384;                  \
    /* P0 */                                                                   \
    READ_A(a1, ASC, 0, 1);                                                     \
    READ_B(BSC, 1);                                                            \
    GLD_CALL(BSN, Bnx, 2);                                                     \
    GLD_CALL(BSN, Bnx, 3);                                                     \
    BAR();                                                                     \
    LGKM0();                                                                   \
    PRIO1(); MFMA16(0, a0, 0); PRIO0();                                        \
    VMCNT(4);                                                                  \
    BAR();                                                                     \
    /* P1 */                                                                   \
    READ_A(a0, ASC, 1, 0);                                                     \
    GLD_CALL(ASN, Anx, 0);                                                     \
    GLD_CALL(ASN, Anx, 2);                                                     \
    BAR();                                                                     \
    LGKM0();                                                                   \
    PRIO1(); MFMA16(0, a1, 4); PRIO0();                                        \
    BAR();                                                                     \
    /* P2 */                                                                   \
    READ_A(a1, ASC, 1, 1);                                                     \
    GLD_CALL(ASN, Anx, 1);                                                     \
    GLD_CALL(ASN, Anx, 3);                                                     \
    BAR();                                                                     \
    LGKM0();                                                                   \
    PRIO1(); MFMA16(1, a0, 0); PRIO0();                                        \
    VMCNT(2);                                                                  \
    BAR();                                                                     \
    /* P3 */                                                                   \
    READ_A(a0, ASN, 0, 0);                                                     \
    READ_B(BSN, 0);                                                            \
    GLD_CALL(BSC, Bnn, 0);                                                     \
    GLD_CALL(BSC, Bnn, 1);                                                     \
    BAR();                                                                     \
    LGKM0();                                                                   \
    PRIO1(); MFMA16(1, a1, 4); PRIO0();                                        \
    BAR();                                                                     \
  }

__global__ __launch_bounds__(512) void gemm8_kernel(
    const unsigned short* __restrict__ At, const unsigned short* __restrict__ Wt,
    const float* __restrict__ bias, float* __restrict__ C) {
  __shared__ __align__(16) unsigned short Asm[2][16384];
  __shared__ __align__(16) unsigned short Bsm[2][16384];
  unsigned short* const As0 = Asm[0];
  unsigned short* const As1 = Asm[1];
  unsigned short* const Bs0 = Bsm[0];
  unsigned short* const Bs1 = Bsm[1];

  const int orig = blockIdx.x;
  const int bid = (orig & 7) * 128 + (orig >> 3);  // XCD swizzle, 1024%8==0
  const int mt = bid >> 2;                         // 0..255
  const int nt = bid & 3;                          // 0..3
  const int batch = mt >> 4;
  const unsigned short* Abase = At + (size_t)mt * 16 * 16384;
  const unsigned short* Bbase = Wt + ((size_t)batch * 4 + nt) * 16 * 16384;

  const int tid = threadIdx.x;
  const int lane = tid & 63;
  const int wid = tid >> 6;
  const int wr = wid >> 2;  // 0..1
  const int wc = wid & 3;   // 0..3
  const int wr2 = wr * 2;
  const int wc2 = wc * 2;
  const int l15 = lane & 15;
  const int kq = lane >> 4;
  const int kq512 = kq * 512;

  f32x4 acc[8][4] = {};
  s16x8 a0[4], a1[4], bfr[8];

  // Prologue: stage tile 0 fully + B(1) calls 0,1; gate; pre-read a0/b[0..3].
  GLD_CALL(Bs0, Bbase, 0);
  GLD_CALL(Bs0, Bbase, 1);
  GLD_CALL(Bs0, Bbase, 2);
  GLD_CALL(Bs0, Bbase, 3);
  GLD_CALL(As0, Abase, 0);
  GLD_CALL(As0, Abase, 2);
  GLD_CALL(As0, Abase, 1);
  GLD_CALL(As0, Abase, 3);
  {
    const unsigned short* B1 = Bbase + 16384;
    GLD_CALL(Bs1, B1, 0);
    GLD_CALL(Bs1, B1, 1);
  }
  VMCNT(2);
  BAR();
  READ_A(a0, As0, 0, 0);
  READ_B(Bs0, 0);

#pragma unroll 1
  for (int it = 0; it < 8; ++it) {
    const int t0 = it * 2;
    TILE_BODY(As0, Bs0, As1, Bs1, t0);
    TILE_BODY(As1, Bs1, As0, Bs0, t0 + 1);
  }

  // Epilogue: bias add + store fp32
  const int m0 = mt * 256, n0 = nt * 256;
#pragma unroll
  for (int n = 0; n < 4; ++n) {
    const int col = n0 + wc * 64 + n * 16 + l15;
    const float bv = bias[col];
#pragma unroll
    for (int m = 0; m < 8; ++m) {
      const int row = m0 + wr * 128 + m * 16 + kq * 4;
#pragma unroll
      for (int j = 0; j < 4; ++j)
        C[(size_t)(row + j) * ND + col] = acc[m][n][j] + bv;
    }
  }
}

// ---------------------------------------------------------------------------
extern "C" void kernel_launch(void* const* d_in, const int* in_sizes, int n_in,
                              void* d_out, int out_size, void* d_ws,
                              size_t ws_size, hipStream_t stream) {
  const float* input = (const float*)d_in[0];
  const float* skill_logits = (const float*)d_in[1];
  const float* weight = (const float*)d_in[2];
  const float* bias = (const float*)d_in[3];
  const float* Askills = (const float*)d_in[4];
  const float* Bskills = (const float*)d_in[5];
  const int* task_ids = (const int*)d_in[6];

  float* wA = (float*)d_ws;                                   // 1 MB
  float* wB = wA + 16 * 16384;                                // 1 MB
  unsigned short* Wt = (unsigned short*)(wB + 16 * 16384);    // 32 MB
  unsigned short* At = Wt + 16ull * 1024 * 1024;              // 128 MB

  route_wab_kernel<<<32, 256, 0, stream>>>(skill_logits, task_ids, Askills,
                                           Bskills, wA, wB);
  aconv_kernel<<<16384, 256, 0, stream>>>(input, At);
  weff_kernel<<<4096, 256, 0, stream>>>(weight, wA, wB, Wt);
  gemm8_kernel<<<1024, 512, 0, stream>>>(At, Wt, bias, (float*)d_out);
}